// Round 1
// baseline (725.421 us; speedup 1.0000x reference)
//
#include <hip/hip_runtime.h>

#define IN1   784
#define HDIM  128
#define KOUTN 64
#define GRIDW 10
#define OUTN  10
#define BROWS 64
#define BK    16
#define KK2   (HDIM*GRIDW)   // 1280

#define RICKER_C 0.86732507f

// ws layout (fp32): [0,12800) coef2 at index i*100 + g*10 + j ; [12800,12810) bias2[j]
__global__ __launch_bounds__(256) void prep_kernel(
    const float* __restrict__ coef, const float* __restrict__ wbias,
    const float* __restrict__ w2, const float* __restrict__ b2,
    float* __restrict__ ws)
{
    int idx = blockIdx.x * 256 + threadIdx.x;
    if (idx < 12800) {
        int i   = idx / 100;
        int rem = idx - i * 100;
        int g   = rem / 10;
        int j   = rem - g * 10;
        float s = 0.f;
        const float* cp = coef + i * GRIDW + g;   // coef[o*1280 + i*10 + g]
        const float* wp = w2 + j * KOUTN;
        #pragma unroll 4
        for (int o = 0; o < KOUTN; ++o)
            s = fmaf(wp[o], cp[o * KK2], s);
        ws[idx] = RICKER_C * s;
    } else if (idx < 12810) {
        int j = idx - 12800;
        float s = b2[j];
        for (int o = 0; o < KOUTN; ++o)
            s = fmaf(w2[j * KOUTN + o], wbias[o], s);
        ws[idx] = s;
    }
}

union SharedU {
    struct { float xt[BK][BROWS + 4]; float wt[BK][HDIM + 4]; } p1; // 4352 + 8448 B
    float coef2[6400];                                              // 25600 B
    float red[16][32][10];                                          // 20480 B
};

__global__ __launch_bounds__(256) void mnist_fused(
    const float* __restrict__ x, const float* __restrict__ w1,
    const float* __restrict__ b1, const float* __restrict__ ws,
    float* __restrict__ out)
{
    __shared__ float h_tile[BROWS][HDIM + 1];   // 64 x 129 = 33024 B
    __shared__ SharedU u;                       // 25600 B  -> total ~57.3 KB

    const int tid  = threadIdx.x;
    const int row0 = blockIdx.x * BROWS;

    // ---------------- phase 1: h = x @ w1^T + b1 ----------------
    {
        const int ty = tid >> 4;          // 0..15 -> rows
        const int tx = tid & 15;          // 0..15 -> cols
        const int r0 = ty * 4, c0 = tx * 8;
        const int lr = tid >> 2;          // 0..63  (x row / w1 row)
        const int lq = tid & 3;           // 0..3   (16-float quad)

        float acc[4][8];
        #pragma unroll
        for (int r = 0; r < 4; ++r)
            #pragma unroll
            for (int c = 0; c < 8; ++c) acc[r][c] = 0.f;

        const float* xrow = x + (size_t)(row0 + lr) * IN1 + lq * 4;
        const float* wrow0 = w1 + (size_t)lr * IN1 + lq * 4;         // i = 0..63
        const float* wrow1 = w1 + (size_t)(lr + 64) * IN1 + lq * 4;  // i = 64..127

        for (int kt = 0; kt < IN1 / BK; ++kt) {
            float4 xv  = *(const float4*)(xrow  + kt * BK);
            float4 wv0 = *(const float4*)(wrow0 + kt * BK);
            float4 wv1 = *(const float4*)(wrow1 + kt * BK);
            __syncthreads();   // previous iter's LDS reads done
            u.p1.xt[lq * 4 + 0][lr] = xv.x;
            u.p1.xt[lq * 4 + 1][lr] = xv.y;
            u.p1.xt[lq * 4 + 2][lr] = xv.z;
            u.p1.xt[lq * 4 + 3][lr] = xv.w;
            u.p1.wt[lq * 4 + 0][lr] = wv0.x;
            u.p1.wt[lq * 4 + 1][lr] = wv0.y;
            u.p1.wt[lq * 4 + 2][lr] = wv0.z;
            u.p1.wt[lq * 4 + 3][lr] = wv0.w;
            u.p1.wt[lq * 4 + 0][lr + 64] = wv1.x;
            u.p1.wt[lq * 4 + 1][lr + 64] = wv1.y;
            u.p1.wt[lq * 4 + 2][lr + 64] = wv1.z;
            u.p1.wt[lq * 4 + 3][lr + 64] = wv1.w;
            __syncthreads();
            #pragma unroll
            for (int kk = 0; kk < BK; ++kk) {
                float a[4], b[8];
                *(float4*)&a[0] = *(const float4*)&u.p1.xt[kk][r0];
                *(float4*)&b[0] = *(const float4*)&u.p1.wt[kk][c0];
                *(float4*)&b[4] = *(const float4*)&u.p1.wt[kk][c0 + 4];
                #pragma unroll
                for (int r = 0; r < 4; ++r)
                    #pragma unroll
                    for (int c = 0; c < 8; ++c)
                        acc[r][c] = fmaf(a[r], b[c], acc[r][c]);
            }
        }
        // write h tile (+ b1)
        float b1r[8];
        #pragma unroll
        for (int c = 0; c < 8; ++c) b1r[c] = b1[c0 + c];
        #pragma unroll
        for (int r = 0; r < 4; ++r)
            #pragma unroll
            for (int c = 0; c < 8; ++c)
                h_tile[r0 + r][c0 + c] = acc[r][c] + b1r[c];
    }

    // ---------------- phase 2: out_partial = ricker(h*k) . coef2 ----------------
    const int rowgrp = tid >> 4;      // 0..15 -> 4 rows each
    const int islice = tid & 15;      // 0..15 -> i-slices (stride-16 interleave)
    const int pr0 = rowgrp * 4;

    float acc2[4][10];
    #pragma unroll
    for (int r = 0; r < 4; ++r)
        #pragma unroll
        for (int j = 0; j < 10; ++j) acc2[r][j] = 0.f;

    for (int stage = 0; stage < 2; ++stage) {
        __syncthreads();   // h_tile ready / previous stage reads done / p1 reads done
        #pragma unroll
        for (int l = 0; l < 7; ++l) {
            int idx4 = l * 256 + tid;
            if (idx4 < 1600)
                *(float4*)&u.coef2[idx4 * 4] =
                    *(const float4*)&ws[stage * 6400 + idx4 * 4];
        }
        __syncthreads();
        #pragma unroll
        for (int m = 0; m < 4; ++m) {
            const int iloc = islice + 16 * m;        // 0..63
            const int ig   = stage * 64 + iloc;      // global i
            float h0 = h_tile[pr0 + 0][ig];
            float h1 = h_tile[pr0 + 1][ig];
            float h2 = h_tile[pr0 + 2][ig];
            float h3 = h_tile[pr0 + 3][ig];
            const float* c2base = &u.coef2[iloc * 100];
            #pragma unroll
            for (int g = 0; g < 10; ++g) {
                const float kg = (float)(g + 1);
                float t0 = h0 * kg, t1 = h1 * kg, t2 = h2 * kg, t3 = h3 * kg;
                float q0 = t0 * t0, q1 = t1 * t1, q2 = t2 * t2, q3 = t3 * t3;
                float p0 = (1.f - q0) * __expf(-0.5f * q0);
                float p1 = (1.f - q1) * __expf(-0.5f * q1);
                float p2 = (1.f - q2) * __expf(-0.5f * q2);
                float p3 = (1.f - q3) * __expf(-0.5f * q3);
                const float* c2 = c2base + g * 10;
                #pragma unroll
                for (int j = 0; j < 10; ++j) {
                    float cv = c2[j];
                    acc2[0][j] = fmaf(p0, cv, acc2[0][j]);
                    acc2[1][j] = fmaf(p1, cv, acc2[1][j]);
                    acc2[2][j] = fmaf(p2, cv, acc2[2][j]);
                    acc2[3][j] = fmaf(p3, cv, acc2[3][j]);
                }
            }
        }
    }

    // ---------------- reduce 16 i-slices and store ----------------
    __syncthreads();   // all coef2 reads done -> reuse union as red
    if (rowgrp < 8) {
        #pragma unroll
        for (int r = 0; r < 4; ++r)
            #pragma unroll
            for (int j = 0; j < 10; ++j)
                u.red[islice][pr0 + r][j] = acc2[r][j];
    }
    __syncthreads();
    for (int idx = tid; idx < 320; idx += 256) {
        int r = idx / 10, j = idx - 10 * (idx / 10);
        float s = 0.f;
        #pragma unroll
        for (int is = 0; is < 16; ++is) s += u.red[is][r][j];
        out[(size_t)(row0 + r) * OUTN + j] = s + ws[12800 + j];
    }
    __syncthreads();
    if (rowgrp >= 8) {
        #pragma unroll
        for (int r = 0; r < 4; ++r)
            #pragma unroll
            for (int j = 0; j < 10; ++j)
                u.red[islice][pr0 - 32 + r][j] = acc2[r][j];
    }
    __syncthreads();
    for (int idx = tid; idx < 320; idx += 256) {
        int r = idx / 10, j = idx - 10 * (idx / 10);
        float s = 0.f;
        #pragma unroll
        for (int is = 0; is < 16; ++is) s += u.red[is][r][j];
        out[(size_t)(row0 + 32 + r) * OUTN + j] = s + ws[12800 + j];
    }
}

extern "C" void kernel_launch(void* const* d_in, const int* in_sizes, int n_in,
                              void* d_out, int out_size, void* d_ws, size_t ws_size,
                              hipStream_t stream) {
    const float* x     = (const float*)d_in[0];
    const float* w1    = (const float*)d_in[1];
    const float* b1    = (const float*)d_in[2];
    const float* coef  = (const float*)d_in[3];
    const float* wbias = (const float*)d_in[4];
    const float* w2    = (const float*)d_in[5];
    const float* b2    = (const float*)d_in[6];
    float* out = (float*)d_out;
    float* ws  = (float*)d_ws;

    const int Brows = in_sizes[0] / IN1;          // 65536
    prep_kernel<<<(12810 + 255) / 256, 256, 0, stream>>>(coef, wbias, w2, b2, ws);
    mnist_fused<<<Brows / BROWS, 256, 0, stream>>>(x, w1, b1, ws, out);
}

// Round 2
// 349.660 us; speedup vs baseline: 2.0746x; 2.0746x over previous
//
#include <hip/hip_runtime.h>

#define STRH 132   // h_tile row stride (floats): 132%32=4 -> spread banks, 16B aligned

typedef short bf16x8 __attribute__((ext_vector_type(8)));
typedef float f32x4 __attribute__((ext_vector_type(4)));

#define MFMA16(a, b, c) __builtin_amdgcn_mfma_f32_16x16x32_bf16((a), (b), (c), 0, 0, 0)

__device__ __forceinline__ unsigned int f2bf_rne(float f) {
    unsigned int u = __float_as_uint(f);
    return (u + 0x7FFFu + ((u >> 16) & 1u)) >> 16;
}
__device__ __forceinline__ float bfbits2f(unsigned int b) {
    return __uint_as_float(b << 16);
}
__device__ __forceinline__ unsigned int pack_hu(float a, float b) {
    // cheap round-half-up bf16 pack (psi path; rel err <= 2^-9)
    unsigned int ua = (__float_as_uint(a) + 0x8000u) >> 16;
    unsigned int ub = (__float_as_uint(b) + 0x8000u) >> 16;
    return ua | (ub << 16);
}
__device__ __forceinline__ uint4 pack8(const unsigned int* b) {
    return make_uint4(b[0] | (b[1] << 16), b[2] | (b[3] << 16),
                      b[4] | (b[5] << 16), b[6] | (b[7] << 16));
}

// ws byte layout:
//   [0, 40960)        c2 frags  bf16 [s=40][lane=64][j=8]  (k' = 32s + 8*(lane>>4) + j, n = lane&15)
//   [40960, 41000)    bias2 fp32 [10]
//   [41472, 246272)   w1hi bf16 [128][800]  (k >= 784 zero-padded)
//   [246272, 451072)  w1lo bf16 [128][800]
#define WS_BYTES_NEEDED 451072

__global__ __launch_bounds__(256) void prep_kernel(
    const float* __restrict__ coef, const float* __restrict__ wbias,
    const float* __restrict__ w2, const float* __restrict__ b2,
    const float* __restrict__ w1, float* __restrict__ ws, int do_w1)
{
    int idx = blockIdx.x * 256 + threadIdx.x;
    if (idx < 20480) {
        // c2 frag element: idx = s*512 + l*8 + j
        int l = (idx >> 3) & 63, j = idx & 7;
        int s = idx >> 9;
        int n = l & 15, q = l >> 4;
        int P = 4 * s + q;
        int g = P >> 4;                 // 0..9
        int i = ((P & 15) << 3) + j;    // 0..127
        float v = 0.f;
        if (n < 10) {
            float sum = 0.f;
            const float* cp = coef + i * 10 + g;   // coef[o*1280 + i*10 + g]
            const float* wp = w2 + n * 64;
            #pragma unroll 8
            for (int o = 0; o < 64; ++o)
                sum = fmaf(wp[o], cp[o * 1280], sum);
            v = 0.8673250706f * sum;    // RICKER_C folded in
        }
        ((unsigned short*)ws)[idx] = (unsigned short)f2bf_rne(v);
    } else if (idx < 20490) {
        int n = idx - 20480;
        float sum = b2[n];
        for (int o = 0; o < 64; ++o)
            sum = fmaf(w2[n * 64 + o], wbias[o], sum);
        ws[10240 + n] = sum;
    } else if (do_w1 && idx >= 20736) {
        int t = idx - 20736;
        if (t < 102400) {
            int n = t / 800, k = t - n * 800;
            unsigned int hi = 0, lo = 0;
            if (k < 784) {
                float f = w1[n * 784 + k];
                hi = f2bf_rne(f);
                lo = f2bf_rne(f - bfbits2f(hi));
            }
            ((unsigned short*)((char*)ws + 41472))[t] = (unsigned short)hi;
            ((unsigned short*)((char*)ws + 246272))[t] = (unsigned short)lo;
        }
    }
}

union StageU {
    struct {
        unsigned short xa_hi[2048], xa_lo[2048];   // [4 tiles][64 lanes][8] frag-linear
        unsigned short wb_hi[4096], wb_lo[4096];   // [8 tiles][64 lanes][8]
    } p1;                                          // 24576 B
    unsigned short c2[10240];                      // half of c2 frags, 20480 B
};

template <bool WSW1>
__global__ __launch_bounds__(256) void mnist_fused(
    const float* __restrict__ x, const float* __restrict__ w1,
    const float* __restrict__ b1, const float* __restrict__ ws,
    float* __restrict__ out)
{
    __shared__ float h_tile[64 * STRH];   // 33792 B
    __shared__ StageU u;                  // 24576 B -> total 58368 B (2 blocks/CU)

    const int tid  = threadIdx.x;
    const int lane = tid & 63;
    const int wv   = tid >> 6;            // wave id = m-tile (16 rows each)
    const long row0 = (long)blockIdx.x * 64;

    // staging roles
    const int sr = tid >> 2, so = tid & 3;    // x: row 0..63, k-octet 0..3
    const int wn = tid >> 1, whh = tid & 1;   // w: row 0..127, k-half(16) 0..1

    const float* xbase = x + (row0 + sr) * 784 + so * 8;
    const unsigned short* w1hi = (const unsigned short*)((const char*)ws + 41472);
    const unsigned short* w1lo = (const unsigned short*)((const char*)ws + 246272);

    f32x4 acc[8];
    #pragma unroll
    for (int T = 0; T < 8; ++T)
        acc[T] = (f32x4){0.f, 0.f, 0.f, 0.f};

    // ---- prefetch kt = 0 ----
    float4 xr0 = ((const float4*)xbase)[0];
    float4 xr1 = ((const float4*)xbase)[1];
    uint4 wh0, wh1, wl0, wl1;
    float4 wf0, wf1, wf2, wf3;
    if (WSW1) {
        const unsigned short* ph = w1hi + wn * 800 + whh * 16;
        const unsigned short* pl = w1lo + wn * 800 + whh * 16;
        wh0 = *(const uint4*)ph;       wh1 = *(const uint4*)(ph + 8);
        wl0 = *(const uint4*)pl;       wl1 = *(const uint4*)(pl + 8);
    } else {
        const float* pw = w1 + wn * 784 + whh * 16;
        wf0 = ((const float4*)pw)[0]; wf1 = ((const float4*)pw)[1];
        wf2 = ((const float4*)pw)[2]; wf3 = ((const float4*)pw)[3];
    }

    // ================= phase 1: h = x @ w1^T + b1 (bf16-split MFMA) =================
    for (int kt = 0; kt < 25; ++kt) {
        __syncthreads();   // previous iteration's frag reads done
        // ---- write x frags (convert fp32 -> hi/lo bf16) ----
        {
            float xf[8] = {xr0.x, xr0.y, xr0.z, xr0.w, xr1.x, xr1.y, xr1.z, xr1.w};
            unsigned int hb[8], lb[8];
            #pragma unroll
            for (int e = 0; e < 8; ++e) {
                hb[e] = f2bf_rne(xf[e]);
                lb[e] = f2bf_rne(xf[e] - bfbits2f(hb[e]));
            }
            int xi = ((sr >> 4) * 64 + so * 16 + (sr & 15)) * 8;
            *(uint4*)&u.p1.xa_hi[xi] = pack8(hb);
            *(uint4*)&u.p1.xa_lo[xi] = pack8(lb);
        }
        // ---- write w frags ----
        {
            int wi0 = ((wn >> 4) * 64 + (2 * whh) * 16 + (wn & 15)) * 8;
            if (WSW1) {
                *(uint4*)&u.p1.wb_hi[wi0]       = wh0;
                *(uint4*)&u.p1.wb_hi[wi0 + 128] = wh1;
                *(uint4*)&u.p1.wb_lo[wi0]       = wl0;
                *(uint4*)&u.p1.wb_lo[wi0 + 128] = wl1;
            } else {
                float wf[16] = {wf0.x, wf0.y, wf0.z, wf0.w, wf1.x, wf1.y, wf1.z, wf1.w,
                                wf2.x, wf2.y, wf2.z, wf2.w, wf3.x, wf3.y, wf3.z, wf3.w};
                unsigned int hb[16], lb[16];
                #pragma unroll
                for (int e = 0; e < 16; ++e) {
                    hb[e] = f2bf_rne(wf[e]);
                    lb[e] = f2bf_rne(wf[e] - bfbits2f(hb[e]));
                }
                *(uint4*)&u.p1.wb_hi[wi0]       = pack8(hb);
                *(uint4*)&u.p1.wb_hi[wi0 + 128] = pack8(hb + 8);
                *(uint4*)&u.p1.wb_lo[wi0]       = pack8(lb);
                *(uint4*)&u.p1.wb_lo[wi0 + 128] = pack8(lb + 8);
            }
        }
        __syncthreads();
        // ---- prefetch kt+1 (in flight during MFMA) ----
        if (kt < 24) {
            int kn = (kt + 1) * 32;
            bool xv = (kn + so * 8) < 784;   // 784 is 8-aligned -> octet fully valid/invalid
            const float4* xp = (const float4*)(xv ? (xbase + kn) : x);
            xr0 = xp[0]; xr1 = xp[1];
            if (!xv) { xr0 = make_float4(0.f, 0.f, 0.f, 0.f); xr1 = xr0; }
            if (WSW1) {
                const unsigned short* ph = w1hi + wn * 800 + kn + whh * 16;
                const unsigned short* pl = w1lo + wn * 800 + kn + whh * 16;
                wh0 = *(const uint4*)ph;  wh1 = *(const uint4*)(ph + 8);
                wl0 = *(const uint4*)pl;  wl1 = *(const uint4*)(pl + 8);
            } else {
                int kw = kn + whh * 16;
                bool wvld = kw < 784;     // 784 is 16-aligned
                const float* pw = wvld ? (w1 + wn * 784 + kw) : w1;
                wf0 = ((const float4*)pw)[0]; wf1 = ((const float4*)pw)[1];
                wf2 = ((const float4*)pw)[2]; wf3 = ((const float4*)pw)[3];
                if (!wvld) {
                    wf0 = make_float4(0.f, 0.f, 0.f, 0.f);
                    wf1 = wf0; wf2 = wf0; wf3 = wf0;
                }
            }
        }
        // ---- MFMA: lane-linear frag reads (conflict-free) ----
        {
            uint4 ta = *(const uint4*)&u.p1.xa_hi[(wv * 64 + lane) * 8];
            uint4 tb = *(const uint4*)&u.p1.xa_lo[(wv * 64 + lane) * 8];
            bf16x8 Ah = __builtin_bit_cast(bf16x8, ta);
            bf16x8 Al = __builtin_bit_cast(bf16x8, tb);
            #pragma unroll
            for (int T = 0; T < 8; ++T) {
                uint4 th = *(const uint4*)&u.p1.wb_hi[(T * 64 + lane) * 8];
                uint4 tl = *(const uint4*)&u.p1.wb_lo[(T * 64 + lane) * 8];
                bf16x8 Bh = __builtin_bit_cast(bf16x8, th);
                bf16x8 Bl = __builtin_bit_cast(bf16x8, tl);
                acc[T] = MFMA16(Ah, Bh, acc[T]);
                acc[T] = MFMA16(Ah, Bl, acc[T]);
                acc[T] = MFMA16(Al, Bh, acc[T]);
            }
        }
    }

    // ---- epilogue: h_tile[m][n] = acc + b1 (C/D: col=lane&15, row=(lane>>4)*4+reg) ----
    {
        const int mb = wv * 16 + (lane >> 4) * 4;
        const int nb = lane & 15;
        #pragma unroll
        for (int T = 0; T < 8; ++T) {
            float bias = b1[T * 16 + nb];
            #pragma unroll
            for (int r = 0; r < 4; ++r)
                h_tile[(mb + r) * STRH + T * 16 + nb] = acc[T][r] + bias;
        }
    }

    // ================= phase 2: out = ricker(h*k) . coef2 (bf16 MFMA) =================
    f32x4 acc2 = (f32x4){0.f, 0.f, 0.f, 0.f};
    const int q = lane >> 4;
    const float* hrow = h_tile + (wv * 16 + (lane & 15)) * STRH;

    for (int half = 0; half < 2; ++half) {
        __syncthreads();   // staging (or previous c2 half) reads done; h_tile visible
        {
            const uint4* src = (const uint4*)ws + half * 1280 + tid;
            uint4* dst = (uint4*)u.c2 + tid;
            #pragma unroll
            for (int c = 0; c < 5; ++c) dst[c * 256] = src[c * 256];
        }
        __syncthreads();
        #pragma unroll 4
        for (int s2 = 0; s2 < 20; ++s2) {
            int P = (half * 20 + s2) * 4 + q;      // k' octet index
            float kg = (float)((P >> 4) + 1);      // wavelet scale g+1
            int i0 = (P & 15) << 3;                // 8 contiguous h cols
            float4 h0 = *(const float4*)(hrow + i0);
            float4 h1 = *(const float4*)(hrow + i0 + 4);
            float hv[8] = {h0.x, h0.y, h0.z, h0.w, h1.x, h1.y, h1.z, h1.w};
            unsigned int pk[4];
            #pragma unroll
            for (int e = 0; e < 8; e += 2) {
                float t0 = hv[e] * kg,   t1 = hv[e + 1] * kg;
                float q0 = t0 * t0,      q1 = t1 * t1;
                float p0 = (1.f - q0) * __expf(-0.5f * q0);
                float p1 = (1.f - q1) * __expf(-0.5f * q1);
                pk[e >> 1] = pack_hu(p0, p1);
            }
            bf16x8 A = __builtin_bit_cast(bf16x8, make_uint4(pk[0], pk[1], pk[2], pk[3]));
            uint4 braw = *(const uint4*)&u.c2[(s2 * 64 + lane) * 8];
            bf16x8 Bf = __builtin_bit_cast(bf16x8, braw);
            acc2 = MFMA16(A, Bf, acc2);
        }
    }

    // ---- store: C/D col = out-channel n, row = local row ----
    {
        const int n = lane & 15;
        if (n < 10) {
            float bias2 = ws[10240 + n];
            const long rb = row0 + wv * 16 + (lane >> 4) * 4;
            #pragma unroll
            for (int r = 0; r < 4; ++r)
                out[(rb + r) * 10 + n] = acc2[r] + bias2;
        }
    }
}

extern "C" void kernel_launch(void* const* d_in, const int* in_sizes, int n_in,
                              void* d_out, int out_size, void* d_ws, size_t ws_size,
                              hipStream_t stream) {
    const float* x     = (const float*)d_in[0];
    const float* w1    = (const float*)d_in[1];
    const float* b1    = (const float*)d_in[2];
    const float* coef  = (const float*)d_in[3];
    const float* wbias = (const float*)d_in[4];
    const float* w2    = (const float*)d_in[5];
    const float* b2    = (const float*)d_in[6];
    float* out = (float*)d_out;
    float* ws  = (float*)d_ws;

    const int Brows = in_sizes[0] / 784;   // 65536
    const bool wsw1 = ws_size >= (size_t)WS_BYTES_NEEDED;

    prep_kernel<<<wsw1 ? 481 : 81, 256, 0, stream>>>(coef, wbias, w2, b2, w1, ws,
                                                     wsw1 ? 1 : 0);
    if (wsw1)
        mnist_fused<true><<<Brows / 64, 256, 0, stream>>>(x, w1, b1, ws, out);
    else
        mnist_fused<false><<<Brows / 64, 256, 0, stream>>>(x, w1, b1, ws, out);
}

// Round 3
// 345.401 us; speedup vs baseline: 2.1002x; 1.0123x over previous
//
#include <hip/hip_runtime.h>

typedef short bf16x8 __attribute__((ext_vector_type(8)));
typedef _Float16 f16x8 __attribute__((ext_vector_type(8)));
typedef float f32x4 __attribute__((ext_vector_type(4)));

#define MFMA_BF16(a, b, c) __builtin_amdgcn_mfma_f32_16x16x32_bf16((a), (b), (c), 0, 0, 0)
#define MFMA_F16(a, b, c)  __builtin_amdgcn_mfma_f32_16x16x32_f16((a), (b), (c), 0, 0, 0)

#define STRH 136          // h_tile row stride in halves: 272 B = 16-aligned, near-conflict-free

__device__ __forceinline__ unsigned int f2bf_rne(float f) {
    unsigned int u = __float_as_uint(f);
    return (u + 0x7FFFu + ((u >> 16) & 1u)) >> 16;
}
__device__ __forceinline__ unsigned int pack_hu(float a, float b) {
    unsigned int ua = (__float_as_uint(a) + 0x8000u) >> 16;
    unsigned int ub = (__float_as_uint(b) + 0x8000u) >> 16;
    return ua | (ub << 16);
}
__device__ __forceinline__ unsigned int pkrtz(float a, float b) {
    return __builtin_bit_cast(unsigned int, __builtin_amdgcn_cvt_pkrtz(a, b));
}

// ws byte layout:
//   [0, 40960)       c2 frags bf16 [s=40][lane=64][j=8]   (P=4s+q, g=P>>4, i=(P&15)*8+j, n=lane&15)
//   [40960, 41000)   bias2 fp32 [10]
//   [41472, 246272)  w1 fp16 frags [kt=25][T=8][lane=64][j=8]  (n=T*16+(lane&15), k=kt*32+(lane>>4)*8+j)
__global__ __launch_bounds__(256) void prep_kernel(
    const float* __restrict__ coef, const float* __restrict__ wbias,
    const float* __restrict__ w2, const float* __restrict__ b2,
    const float* __restrict__ w1, float* __restrict__ ws)
{
    int idx = blockIdx.x * 256 + threadIdx.x;
    if (idx < 20480) {
        int l = (idx >> 3) & 63, j = idx & 7;
        int s = idx >> 9;
        int n = l & 15, q = l >> 4;
        int P = 4 * s + q;
        int g = P >> 4;                 // 0..9
        int i = ((P & 15) << 3) + j;    // 0..127
        float v = 0.f;
        if (n < 10) {
            float sum = 0.f;
            const float* cp = coef + i * 10 + g;   // coef[o*1280 + i*10 + g]
            const float* wp = w2 + n * 64;
            #pragma unroll 8
            for (int o = 0; o < 64; ++o)
                sum = fmaf(wp[o], cp[o * 1280], sum);
            v = 0.8673250706f * sum;    // RICKER_C folded in
        }
        ((unsigned short*)ws)[idx] = (unsigned short)f2bf_rne(v);
    } else if (idx < 20490) {
        int n = idx - 20480;
        float sum = b2[n];
        for (int o = 0; o < 64; ++o)
            sum = fmaf(w2[n * 64 + o], wbias[o], sum);
        ws[10240 + n] = sum;
    } else if (idx >= 20736) {
        int t = idx - 20736;
        if (t < 102400) {
            int n = t / 800, k = t - n * 800;
            _Float16 hv = (_Float16)0.f;
            if (k < 784) hv = (_Float16)w1[n * 784 + k];
            int kt = k >> 5, ko = k & 31;
            int qq = ko >> 3, j = ko & 7;
            int T = n >> 4, ln = qq * 16 + (n & 15);
            int slot = ((kt * 8 + T) * 64 + ln) * 8 + j;
            ((unsigned short*)((char*)ws + 41472))[slot] =
                __builtin_bit_cast(unsigned short, hv);
        }
    }
}

__global__ __launch_bounds__(256, 4) void mnist_fused(
    const float* __restrict__ x, const float* __restrict__ b1,
    const float* __restrict__ ws, float* __restrict__ out)
{
    __shared__ __align__(16) unsigned short h_tile[64 * STRH];  // 17408 B
    __shared__ __align__(16) unsigned short c2buf[10240];       // 20480 B  (total 37.9 KB)

    const int tid  = threadIdx.x;
    const int lane = tid & 63;
    const int wv   = tid >> 6;         // wave = m-tile (16 rows)
    const int m    = lane & 15;
    const int q    = lane >> 4;
    const long row0 = (long)blockIdx.x * 64;

    // ---- stage c2 half 0 (overlaps with GEMM) ----
    {
        const uint4* src = (const uint4*)ws + tid;
        uint4* dst = (uint4*)c2buf + tid;
        #pragma unroll
        for (int c = 0; c < 5; ++c) dst[c * 256] = src[c * 256];
    }

    // ================= phase 1: h = x @ w1^T + b1  (fp16 MFMA, no LDS, no barriers) ==========
    const unsigned short* w1f = (const unsigned short*)((const char*)ws + 41472);
    const float* pa = x + (row0 + wv * 16 + m) * 784 + q * 8;

    f32x4 acc[8];
    #pragma unroll
    for (int T = 0; T < 8; ++T) acc[T] = (f32x4){0.f, 0.f, 0.f, 0.f};

    for (int kt = 0; kt < 24; ++kt) {
        float4 a0 = *(const float4*)(pa + kt * 32);
        float4 a1 = *(const float4*)(pa + kt * 32 + 4);
        uint4 b[8];
        #pragma unroll
        for (int T = 0; T < 8; ++T)
            b[T] = *(const uint4*)(w1f + kt * 4096 + T * 512 + lane * 8);
        uint4 ap = make_uint4(pkrtz(a0.x, a0.y), pkrtz(a0.z, a0.w),
                              pkrtz(a1.x, a1.y), pkrtz(a1.z, a1.w));
        f16x8 A = __builtin_bit_cast(f16x8, ap);
        #pragma unroll
        for (int T = 0; T < 8; ++T)
            acc[T] = MFMA_F16(A, __builtin_bit_cast(f16x8, b[T]), acc[T]);
    }
    {   // kt = 24 tail: k = 768 + q*8; valid only for q < 2 (k < 784)
        float4 z4 = make_float4(0.f, 0.f, 0.f, 0.f);
        const float* ps = (q < 2) ? (pa + 768) : pa;   // safe address
        float4 a0 = (q < 2) ? *(const float4*)(ps)     : z4;
        float4 a1 = (q < 2) ? *(const float4*)(ps + 4) : z4;
        uint4 b[8];
        #pragma unroll
        for (int T = 0; T < 8; ++T)
            b[T] = *(const uint4*)(w1f + 24 * 4096 + T * 512 + lane * 8);
        uint4 ap = make_uint4(pkrtz(a0.x, a0.y), pkrtz(a0.z, a0.w),
                              pkrtz(a1.x, a1.y), pkrtz(a1.z, a1.w));
        f16x8 A = __builtin_bit_cast(f16x8, ap);
        #pragma unroll
        for (int T = 0; T < 8; ++T)
            acc[T] = MFMA_F16(A, __builtin_bit_cast(f16x8, b[T]), acc[T]);
    }

    // ---- epilogue: h_tile (fp16) = acc + b1 ;  C/D: col=lane&15, row=q*4+reg ----
    {
        #pragma unroll
        for (int T = 0; T < 8; ++T) {
            float bias = b1[T * 16 + m];
            #pragma unroll
            for (int r = 0; r < 4; ++r) {
                _Float16 hv = (_Float16)(acc[T][r] + bias);
                h_tile[(wv * 16 + q * 4 + r) * STRH + T * 16 + m] =
                    __builtin_bit_cast(unsigned short, hv);
            }
        }
    }

    // ================= phase 2: out = ricker(h*k) . coef2  (bf16 MFMA) =================
    f32x4 acc2 = (f32x4){0.f, 0.f, 0.f, 0.f};
    const unsigned short* hrow = h_tile + (wv * 16 + m) * STRH;

    #pragma unroll
    for (int half_ = 0; half_ < 2; ++half_) {
        if (half_ == 1) {
            __syncthreads();   // half-0 c2 reads done
            const uint4* src = (const uint4*)ws + 1280 + tid;
            uint4* dst = (uint4*)c2buf + tid;
            #pragma unroll
            for (int c = 0; c < 5; ++c) dst[c * 256] = src[c * 256];
        }
        __syncthreads();       // h_tile + c2 stage visible
        #pragma unroll 4
        for (int s2 = 0; s2 < 20; ++s2) {
            int P = (half_ * 20 + s2) * 4 + q;
            float kg = (float)((P >> 4) + 1);
            int i0 = (P & 15) << 3;
            uint4 hraw = *(const uint4*)(hrow + i0);
            f16x8 hh = __builtin_bit_cast(f16x8, hraw);
            unsigned int pk[4];
            #pragma unroll
            for (int e = 0; e < 8; e += 2) {
                float t0 = (float)hh[e] * kg;
                float t1 = (float)hh[e + 1] * kg;
                float z0 = t0 * t0, z1 = t1 * t1;
                float p0 = (1.f - z0) * __expf(-0.5f * z0);
                float p1 = (1.f - z1) * __expf(-0.5f * z1);
                pk[e >> 1] = pack_hu(p0, p1);
            }
            bf16x8 A = __builtin_bit_cast(bf16x8, make_uint4(pk[0], pk[1], pk[2], pk[3]));
            uint4 braw = *(const uint4*)&c2buf[(s2 * 64 + lane) * 8];
            acc2 = MFMA_BF16(A, __builtin_bit_cast(bf16x8, braw), acc2);
        }
    }

    // ---- store: C/D col = out-channel n, row = q*4+r within wave's 16-row tile ----
    if (m < 10) {
        float bias2 = ws[10240 + m];
        const long rb = row0 + wv * 16 + q * 4;
        #pragma unroll
        for (int r = 0; r < 4; ++r)
            out[(rb + r) * 10 + m] = acc2[r] + bias2;
    }
}

extern "C" void kernel_launch(void* const* d_in, const int* in_sizes, int n_in,
                              void* d_out, int out_size, void* d_ws, size_t ws_size,
                              hipStream_t stream) {
    const float* x     = (const float*)d_in[0];
    const float* w1    = (const float*)d_in[1];
    const float* b1    = (const float*)d_in[2];
    const float* coef  = (const float*)d_in[3];
    const float* wbias = (const float*)d_in[4];
    const float* w2    = (const float*)d_in[5];
    const float* b2    = (const float*)d_in[6];
    float* out = (float*)d_out;
    float* ws  = (float*)d_ws;

    const int Brows = in_sizes[0] / 784;   // 65536
    prep_kernel<<<481, 256, 0, stream>>>(coef, wbias, w2, b2, w1, ws);
    mnist_fused<<<Brows / 64, 256, 0, stream>>>(x, b1, ws, out);
}

// Round 4
// 325.402 us; speedup vs baseline: 2.2293x; 1.0615x over previous
//
#include <hip/hip_runtime.h>

typedef _Float16 f16x8 __attribute__((ext_vector_type(8)));
typedef float f32x4 __attribute__((ext_vector_type(4)));

#define MFMA_F16(a, b, c) __builtin_amdgcn_mfma_f32_16x16x32_f16((a), (b), (c), 0, 0, 0)
#define STRH 136   // h_tile row stride in halves

__device__ __forceinline__ unsigned int pkrtz(float a, float b) {
    return __builtin_bit_cast(unsigned int, __builtin_amdgcn_cvt_pkrtz(a, b));
}

#define GLDS(g, l) __builtin_amdgcn_global_load_lds(                      \
    (const __attribute__((address_space(1))) void*)(g),                   \
    (__attribute__((address_space(3))) void*)(l), 16, 0, 0)

// ws byte layout:
//   [0, 40960)       c2 frags fp16 [s=40][lane=64][j=8]  (P=4s+q, g=P>>4, i=(P&15)*8+j, n=lane&15)
//   [40960, 41000)   bias2 fp32 [10]
//   [41472, 246272)  w1 fp16 frags [kt=25][T=8][lane=64][j=8] (n=T*16+(lane&15), k=kt*32+(lane>>4)*8+j)
__global__ __launch_bounds__(256) void prep_kernel(
    const float* __restrict__ coef, const float* __restrict__ wbias,
    const float* __restrict__ w2, const float* __restrict__ b2,
    const float* __restrict__ w1, float* __restrict__ ws)
{
    int idx = blockIdx.x * 256 + threadIdx.x;
    if (idx < 20480) {
        int l = (idx >> 3) & 63, j = idx & 7;
        int s = idx >> 9;
        int n = l & 15, q = l >> 4;
        int P = 4 * s + q;
        int g = P >> 4;                 // 0..9
        int i = ((P & 15) << 3) + j;    // 0..127
        float v = 0.f;
        if (n < 10) {
            float sum = 0.f;
            const float* cp = coef + i * 10 + g;   // coef[o*1280 + i*10 + g]
            const float* wp = w2 + n * 64;
            #pragma unroll 8
            for (int o = 0; o < 64; ++o)
                sum = fmaf(wp[o], cp[o * 1280], sum);
            v = 0.8673250706f * sum;    // RICKER_C folded in
        }
        _Float16 hv = (_Float16)v;
        ((unsigned short*)ws)[idx] = __builtin_bit_cast(unsigned short, hv);
    } else if (idx < 20490) {
        int n = idx - 20480;
        float sum = b2[n];
        for (int o = 0; o < 64; ++o)
            sum = fmaf(w2[n * 64 + o], wbias[o], sum);
        ws[10240 + n] = sum;
    } else if (idx >= 20736) {
        int t = idx - 20736;
        if (t < 102400) {
            int n = t / 800, k = t - n * 800;
            _Float16 hv = (_Float16)0.f;
            if (k < 784) hv = (_Float16)w1[n * 784 + k];
            int kt = k >> 5, ko = k & 31;
            int qq = ko >> 3, j = ko & 7;
            int T = n >> 4, ln = qq * 16 + (n & 15);
            int slot = ((kt * 8 + T) * 64 + ln) * 8 + j;
            ((unsigned short*)((char*)ws + 41472))[slot] =
                __builtin_bit_cast(unsigned short, hv);
        }
    }
}

__global__ __launch_bounds__(256, 4) void mnist_fused(
    const float* __restrict__ x, const float* __restrict__ b1,
    const float* __restrict__ ws, float* __restrict__ out)
{
    __shared__ __align__(16) unsigned short Bbuf[2][4096];      // 16384 B (double-buffered w1 kt-tile)
    __shared__ __align__(16) unsigned short h_tile[64 * STRH];  // 17408 B  -> 33.8 KB total, 4 blk/CU

    const int tid  = threadIdx.x;
    const int lane = tid & 63;
    const int wv   = tid >> 6;         // wave = m-tile (16 rows)
    const int m    = lane & 15;
    const int q    = lane >> 4;
    const long row0 = (long)blockIdx.x * 64;

    const char* w1f = (const char*)ws + 41472;
    const float* pa = x + (row0 + wv * 16 + m) * 784 + q * 8;

    // ---- stage B tile kt=0 into Bbuf[0] (each wave: 2 KB via 2 async calls) ----
    {
        const char* g = w1f + wv * 2048 + lane * 16;
        char* l = (char*)&Bbuf[0][0] + wv * 2048;
        GLDS(g, l);
        GLDS(g + 1024, l + 1024);
    }

    f32x4 acc[8];
    #pragma unroll
    for (int T = 0; T < 8; ++T) acc[T] = (f32x4){0.f, 0.f, 0.f, 0.f};

    // ---- prefetch x for kt=0 ----
    float4 xc0 = *(const float4*)pa;
    float4 xc1 = *(const float4*)(pa + 4);

    // ================= phase 1: h = x @ w1^T + b1 (fp16 MFMA, LDS dbuf for B) ==========
    for (int kt = 0; kt < 25; ++kt) {
        __syncthreads();               // Bbuf[kt&1] staged; prev reads retired
        const int cur = kt & 1;
        if (kt < 24) {                 // async-stage next B tile (in flight thru MFMAs)
            const char* g = w1f + (kt + 1) * 8192 + wv * 2048 + lane * 16;
            char* l = (char*)&Bbuf[cur ^ 1][0] + wv * 2048;
            GLDS(g, l);
            GLDS(g + 1024, l + 1024);
        }
        float4 xn0 = xc0, xn1 = xc1;   // prefetch x for kt+1
        if (kt < 24) {
            int kn = (kt + 1) * 32;
            // kt+1==24, q>=2 -> k>=784: B frags are zero there, any finite A ok; clamp addr
            const float* p = (kn + q * 8 < 784) ? (pa + kn) : pa;
            xn0 = *(const float4*)p;
            xn1 = *(const float4*)(p + 4);
        }
        uint4 ap = make_uint4(pkrtz(xc0.x, xc0.y), pkrtz(xc0.z, xc0.w),
                              pkrtz(xc1.x, xc1.y), pkrtz(xc1.z, xc1.w));
        f16x8 A = __builtin_bit_cast(f16x8, ap);
        #pragma unroll
        for (int T = 0; T < 8; ++T) {
            uint4 braw = *(const uint4*)&Bbuf[cur][T * 512 + lane * 8];
            acc[T] = MFMA_F16(A, __builtin_bit_cast(f16x8, braw), acc[T]);
        }
        xc0 = xn0; xc1 = xn1;
    }

    // ---- epilogue: h_tile (fp16) = acc + b1 ;  C/D: col=lane&15, row=q*4+reg ----
    #pragma unroll
    for (int T = 0; T < 8; ++T) {
        float bias = b1[T * 16 + m];
        #pragma unroll
        for (int r = 0; r < 4; ++r) {
            _Float16 hv = (_Float16)(acc[T][r] + bias);
            h_tile[(wv * 16 + q * 4 + r) * STRH + T * 16 + m] =
                __builtin_bit_cast(unsigned short, hv);
        }
    }
    __syncthreads();

    // ================= phase 2: out = ricker(h*k) . coef2 (fp16 MFMA, c2 from L2) ==========
    f32x4 acc2 = (f32x4){0.f, 0.f, 0.f, 0.f};
    const unsigned short* hrow = h_tile + (wv * 16 + m) * STRH;
    const uint4* c2g = (const uint4*)ws;

    #pragma unroll 8
    for (int s2 = 0; s2 < 40; ++s2) {
        int P = s2 * 4 + q;
        float kg = (float)((P >> 4) + 1);
        int i0 = (P & 15) << 3;
        uint4 hraw = *(const uint4*)(hrow + i0);
        f16x8 hh = __builtin_bit_cast(f16x8, hraw);
        unsigned int pk[4];
        #pragma unroll
        for (int e = 0; e < 8; e += 2) {
            float t0 = (float)hh[e] * kg;
            float t1 = (float)hh[e + 1] * kg;
            float z0 = t0 * t0, z1 = t1 * t1;
            float p0 = (1.f - z0) * __expf(-0.5f * z0);
            float p1 = (1.f - z1) * __expf(-0.5f * z1);
            pk[e >> 1] = pkrtz(p0, p1);
        }
        uint4 braw = c2g[s2 * 64 + lane];
        acc2 = MFMA_F16(__builtin_bit_cast(f16x8, make_uint4(pk[0], pk[1], pk[2], pk[3])),
                        __builtin_bit_cast(f16x8, braw), acc2);
    }

    // ---- store: C/D col = out-channel n, row = q*4+r within wave's 16-row tile ----
    if (m < 10) {
        float bias2 = ws[10240 + m];
        const long rb = row0 + wv * 16 + q * 4;
        #pragma unroll
        for (int r = 0; r < 4; ++r)
            out[(rb + r) * 10 + m] = acc2[r] + bias2;
    }
}

extern "C" void kernel_launch(void* const* d_in, const int* in_sizes, int n_in,
                              void* d_out, int out_size, void* d_ws, size_t ws_size,
                              hipStream_t stream) {
    const float* x     = (const float*)d_in[0];
    const float* w1    = (const float*)d_in[1];
    const float* b1    = (const float*)d_in[2];
    const float* coef  = (const float*)d_in[3];
    const float* wbias = (const float*)d_in[4];
    const float* w2    = (const float*)d_in[5];
    const float* b2    = (const float*)d_in[6];
    float* out = (float*)d_out;
    float* ws  = (float*)d_ws;

    const int Brows = in_sizes[0] / 784;   // 65536
    prep_kernel<<<481, 256, 0, stream>>>(coef, wbias, w2, b2, w1, ws);
    mnist_fused<<<Brows / 64, 256, 0, stream>>>(x, b1, ws, out);
}

// Round 5
// 319.988 us; speedup vs baseline: 2.2670x; 1.0169x over previous
//
#include <hip/hip_runtime.h>

typedef _Float16 f16x8 __attribute__((ext_vector_type(8)));
typedef float f32x4 __attribute__((ext_vector_type(4)));

#define MFMA_F16(a, b, c) __builtin_amdgcn_mfma_f32_16x16x32_f16((a), (b), (c), 0, 0, 0)
#define STRH 136   // h_tile row stride in halves

__device__ __forceinline__ unsigned int pkrtz(float a, float b) {
    return __builtin_bit_cast(unsigned int, __builtin_amdgcn_cvt_pkrtz(a, b));
}

#define GLDS(g, l) __builtin_amdgcn_global_load_lds(                      \
    (const __attribute__((address_space(1))) void*)(g),                   \
    (__attribute__((address_space(3))) void*)(l), 16, 0, 0)

// ws byte layout:
//   [0, 40960)       c2 frags fp16 [s=40][lane=64][j=8]  (P=4s+q, g=P>>4, i=(P&15)*8+j, n=lane&15)
//   [40960, 41000)   bias2 fp32 [10]
//   [41472, 246272)  w1 fp16 frags [kt=25][T=8][lane=64][j=8] (n=T*16+(lane&15), k=kt*32+(lane>>4)*8+j)
__global__ __launch_bounds__(256) void prep_kernel(
    const float* __restrict__ coef, const float* __restrict__ wbias,
    const float* __restrict__ w2, const float* __restrict__ b2,
    const float* __restrict__ w1, float* __restrict__ ws)
{
    int idx = blockIdx.x * 256 + threadIdx.x;
    if (idx < 20480) {
        int l = (idx >> 3) & 63, j = idx & 7;
        int s = idx >> 9;
        int n = l & 15, q = l >> 4;
        int P = 4 * s + q;
        int g = P >> 4;                 // 0..9
        int i = ((P & 15) << 3) + j;    // 0..127
        float v = 0.f;
        if (n < 10) {
            float sum = 0.f;
            const float* cp = coef + i * 10 + g;   // coef[o*1280 + i*10 + g]
            const float* wp = w2 + n * 64;
            #pragma unroll 8
            for (int o = 0; o < 64; ++o)
                sum = fmaf(wp[o], cp[o * 1280], sum);
            v = 0.8673250706f * sum;    // RICKER_C folded in
        }
        _Float16 hv = (_Float16)v;
        ((unsigned short*)ws)[idx] = __builtin_bit_cast(unsigned short, hv);
    } else if (idx < 20490) {
        int n = idx - 20480;
        float sum = b2[n];
        for (int o = 0; o < 64; ++o)
            sum = fmaf(w2[n * 64 + o], wbias[o], sum);
        ws[10240 + n] = sum;
    } else if (idx >= 20736) {
        int t = idx - 20736;
        if (t < 102400) {
            int n = t / 800, k = t - n * 800;
            _Float16 hv = (_Float16)0.f;
            if (k < 784) hv = (_Float16)w1[n * 784 + k];
            int kt = k >> 5, ko = k & 31;
            int qq = ko >> 3, j = ko & 7;
            int T = n >> 4, ln = qq * 16 + (n & 15);
            int slot = ((kt * 8 + T) * 64 + ln) * 8 + j;
            ((unsigned short*)((char*)ws + 41472))[slot] =
                __builtin_bit_cast(unsigned short, hv);
        }
    }
}

// launch_bounds(256,2): 256-VGPR budget -> NO scratch spills (R3 spilled ~30
// dwords/thread at the (256,4)/64-VGPR allocation: WRITE_SIZE 30 MB vs 2.6 MB out).
__global__ __launch_bounds__(256, 2) void mnist_fused(
    const float* __restrict__ x, const float* __restrict__ b1,
    const float* __restrict__ ws, float* __restrict__ out)
{
    __shared__ __align__(16) unsigned short Bbuf[2][4096];      // 16384 B (dbuf w1 kt-tile)
    __shared__ __align__(16) unsigned short h_tile[64 * STRH];  // 17408 B -> 33.8 KB total

    const int tid  = threadIdx.x;
    const int lane = tid & 63;
    const int wv   = tid >> 6;         // wave = m-tile (16 rows)
    const int m    = lane & 15;
    const int q    = lane >> 4;
    const long row0 = (long)blockIdx.x * 64;

    const char* w1f = (const char*)ws + 41472;
    const float* pa = x + (row0 + wv * 16 + m) * 784 + q * 8;

    // ---- stage B tile kt=0 into Bbuf[0] (each wave: 2 KB via 2 async calls) ----
    {
        const char* g = w1f + wv * 2048 + lane * 16;
        char* l = (char*)&Bbuf[0][0] + wv * 2048;
        GLDS(g, l);
        GLDS(g + 1024, l + 1024);
    }

    f32x4 acc[8];
    #pragma unroll
    for (int T = 0; T < 8; ++T) acc[T] = (f32x4){0.f, 0.f, 0.f, 0.f};

    // ---- prefetch x for kt=0 ----
    float4 xc0 = *(const float4*)pa;
    float4 xc1 = *(const float4*)(pa + 4);

    // ================= phase 1: h = x @ w1^T + b1 (fp16 MFMA, LDS dbuf for B) ==========
    for (int kt = 0; kt < 25; ++kt) {
        __syncthreads();               // Bbuf[kt&1] staged; prev reads retired
        const int cur = kt & 1;
        if (kt < 24) {                 // async-stage next B tile (in flight thru MFMAs)
            const char* g = w1f + (kt + 1) * 8192 + wv * 2048 + lane * 16;
            char* l = (char*)&Bbuf[cur ^ 1][0] + wv * 2048;
            GLDS(g, l);
            GLDS(g + 1024, l + 1024);
        }
        float4 xn0 = xc0, xn1 = xc1;   // prefetch x for kt+1
        if (kt < 24) {
            int kn = (kt + 1) * 32;
            // kt+1==24, q>=2 -> k>=784: B frags are zero there, any finite A ok; clamp addr
            const float* p = (kn + q * 8 < 784) ? (pa + kn) : pa;
            xn0 = *(const float4*)p;
            xn1 = *(const float4*)(p + 4);
        }
        uint4 ap = make_uint4(pkrtz(xc0.x, xc0.y), pkrtz(xc0.z, xc0.w),
                              pkrtz(xc1.x, xc1.y), pkrtz(xc1.z, xc1.w));
        f16x8 A = __builtin_bit_cast(f16x8, ap);
        #pragma unroll
        for (int T = 0; T < 8; ++T) {
            uint4 braw = *(const uint4*)&Bbuf[cur][T * 512 + lane * 8];
            acc[T] = MFMA_F16(A, __builtin_bit_cast(f16x8, braw), acc[T]);
        }
        xc0 = xn0; xc1 = xn1;
    }

    // ---- epilogue: h_tile (fp16) = acc + b1 ;  C/D: col=lane&15, row=q*4+reg ----
    #pragma unroll
    for (int T = 0; T < 8; ++T) {
        float bias = b1[T * 16 + m];
        #pragma unroll
        for (int r = 0; r < 4; ++r) {
            _Float16 hv = (_Float16)(acc[T][r] + bias);
            h_tile[(wv * 16 + q * 4 + r) * STRH + T * 16 + m] =
                __builtin_bit_cast(unsigned short, hv);
        }
    }
    __syncthreads();

    // ================= phase 2: out = ricker(h*k) . coef2 (fp16 MFMA, c2 from L2) ==========
    f32x4 acc2 = (f32x4){0.f, 0.f, 0.f, 0.f};
    const unsigned short* hrow = h_tile + (wv * 16 + m) * STRH;
    const uint4* c2g = (const uint4*)ws;

    #pragma unroll 4
    for (int s2 = 0; s2 < 40; ++s2) {
        int P = s2 * 4 + q;
        float kg = (float)((P >> 4) + 1);
        int i0 = (P & 15) << 3;
        uint4 hraw = *(const uint4*)(hrow + i0);
        f16x8 hh = __builtin_bit_cast(f16x8, hraw);
        unsigned int pk[4];
        #pragma unroll
        for (int e = 0; e < 8; e += 2) {
            float t0 = (float)hh[e] * kg;
            float t1 = (float)hh[e + 1] * kg;
            float z0 = t0 * t0, z1 = t1 * t1;
            float p0 = (1.f - z0) * __expf(-0.5f * z0);
            float p1 = (1.f - z1) * __expf(-0.5f * z1);
            pk[e >> 1] = pkrtz(p0, p1);
        }
        uint4 braw = c2g[s2 * 64 + lane];
        acc2 = MFMA_F16(__builtin_bit_cast(f16x8, make_uint4(pk[0], pk[1], pk[2], pk[3])),
                        __builtin_bit_cast(f16x8, braw), acc2);
    }

    // ---- store: C/D col = out-channel n, row = q*4+r within wave's 16-row tile ----
    if (m < 10) {
        float bias2 = ws[10240 + m];
        const long rb = row0 + wv * 16 + q * 4;
        #pragma unroll
        for (int r = 0; r < 4; ++r)
            out[(rb + r) * 10 + m] = acc2[r] + bias2;
    }
}

extern "C" void kernel_launch(void* const* d_in, const int* in_sizes, int n_in,
                              void* d_out, int out_size, void* d_ws, size_t ws_size,
                              hipStream_t stream) {
    const float* x     = (const float*)d_in[0];
    const float* w1    = (const float*)d_in[1];
    const float* b1    = (const float*)d_in[2];
    const float* coef  = (const float*)d_in[3];
    const float* wbias = (const float*)d_in[4];
    const float* w2    = (const float*)d_in[5];
    const float* b2    = (const float*)d_in[6];
    float* out = (float*)d_out;
    float* ws  = (float*)d_ws;

    const int Brows = in_sizes[0] / 784;   // 65536
    prep_kernel<<<481, 256, 0, stream>>>(coef, wbias, w2, b2, w1, ws);
    mnist_fused<<<Brows / 64, 256, 0, stream>>>(x, b1, ws, out);
}